// Round 3
// baseline (234.308 us; speedup 1.0000x reference)
//
#include <hip/hip_runtime.h>

// BiCutLoss: output [B,L,2] f32, labels [B,L] i32 -> scalar f32.
// Per row: cut = last j with out1 <= out0 (else L); loss = sum_{j<cut} out1*r1 / B.
// r1 = (label==1) ? -3.6/log2(j+2) : 0.065.

#define LROW 4096
#define BROW 4096
#define BDIM 256
#define PAIRS_PER_THREAD (LROW / (2 * BDIM))  // 8 pairs -> 16 elements/thread

__global__ __launch_bounds__(BDIM) void bicut_loss_kernel(
    const float* __restrict__ out,
    const int* __restrict__ labels,
    float* __restrict__ loss) {
    const int row = blockIdx.x;
    const int tid = threadIdx.x;
    // Row base: each row is LROW float2 pairs = LROW/2 float4s.
    const float4* rowp4 = reinterpret_cast<const float4*>(out + (size_t)row * LROW * 2);
    const int2* labp2 = reinterpret_cast<const int2*>(labels + (size_t)row * LROW);

    float val0[PAIRS_PER_THREAD];
    float val1[PAIRS_PER_THREAD];
    int zmax = -1;  // last j where temp==0 (i.e. !(out1 > out0))
#pragma unroll
    for (int it = 0; it < PAIRS_PER_THREAD; ++it) {
        const int p = it * BDIM + tid;      // pair index, covers j0=2p, j1=2p+1
        const float4 o = rowp4[p];          // (ch0[j0], ch1[j0], ch0[j1], ch1[j1])
        const int2 lab = labp2[p];
        const int j0 = 2 * p;
        const int j1 = 2 * p + 1;
        const float pr0 = -3.6f / __log2f((float)j0 + 2.0f);
        const float pr1 = -3.6f / __log2f((float)j1 + 2.0f);
        val0[it] = o.y * ((lab.x == 1) ? pr0 : 0.065f);
        val1[it] = o.w * ((lab.y == 1) ? pr1 : 0.065f);
        if (!(o.y > o.x)) zmax = j0;        // argmax tie -> 0 => temp==0 iff !(o1 > o0)
        if (!(o.w > o.z)) zmax = j1;        // j1 > j0, so assign unconditionally after
    }

    // ---- block-reduce max(zmax) over 4 waves ----
    __shared__ int smax[BDIM / 64];
    __shared__ float ssum[BDIM / 64];
    const int wid = tid >> 6;
    const int lane = tid & 63;
#pragma unroll
    for (int off = 32; off > 0; off >>= 1)
        zmax = max(zmax, __shfl_down(zmax, off));
    if (lane == 0) smax[wid] = zmax;
    __syncthreads();
    const int m01 = max(smax[0], smax[1]);
    const int m23 = max(smax[2], smax[3]);
    const int mall = max(m01, m23);
    const int cut = (mall < 0) ? LROW : mall;  // all-ones row => cut = L

    // ---- conditional sum from registers, then block-reduce ----
    float s = 0.0f;
#pragma unroll
    for (int it = 0; it < PAIRS_PER_THREAD; ++it) {
        const int p = it * BDIM + tid;
        const int j0 = 2 * p;
        const int j1 = 2 * p + 1;
        if (j0 < cut) s += val0[it];
        if (j1 < cut) s += val1[it];
    }
#pragma unroll
    for (int off = 32; off > 0; off >>= 1)
        s += __shfl_down(s, off);
    if (lane == 0) ssum[wid] = s;
    __syncthreads();
    if (tid == 0) {
        const float bs = (ssum[0] + ssum[1] + ssum[2] + ssum[3]) * (1.0f / (float)BROW);
        atomicAdd(loss, bs);
    }
}

extern "C" void kernel_launch(void* const* d_in, const int* in_sizes, int n_in,
                              void* d_out, int out_size, void* d_ws, size_t ws_size,
                              hipStream_t stream) {
    const float* out = (const float*)d_in[0];
    const int* labels = (const int*)d_in[1];
    float* loss = (float*)d_out;

    // Harness poisons d_out to 0xAA before every timed launch -> zero it ourselves.
    hipMemsetAsync(loss, 0, sizeof(float), stream);
    bicut_loss_kernel<<<BROW, BDIM, 0, stream>>>(out, labels, loss);
}

// Round 4
// 230.262 us; speedup vs baseline: 1.0176x; 1.0176x over previous
//
#include <hip/hip_runtime.h>

// BiCutLoss: output [B,L,2] f32, labels [B,L] i32 -> scalar f32.
// Per row: cut = last j with out1 <= out0 (else L); loss = sum_{j<cut} out1*r1 / B.
// r1 = (label==1) ? -3.6/log2(j+2) : 0.065.
//
// Two-kernel structure: per-row partial -> d_ws[row], then one tiny block
// reduces the 4096 partials. (Round-3 counters: 87us with VALUBusy 13% and
// HBM 14% => serialization suspected on the single-address atomicAdd from
// 4096 blocks ping-ponging across 8 XCD L2s.)

#define LROW 4096
#define BROW 4096
#define BDIM 512
#define NPAIRS (LROW / 2)           // 2048 float4-pairs per row
#define K_ITERS (NPAIRS / BDIM)     // 4 pairs/thread -> 8 elements/thread

__global__ __launch_bounds__(BDIM) void bicut_partial_kernel(
    const float* __restrict__ out,
    const int* __restrict__ labels,
    float* __restrict__ partial) {
    const int row = blockIdx.x;
    const int tid = threadIdx.x;
    const float4* rowp4 = reinterpret_cast<const float4*>(out + (size_t)row * LROW * 2);
    const int2* labp2 = reinterpret_cast<const int2*>(labels + (size_t)row * LROW);

    // Issue ALL global loads first (max memory-level parallelism).
    float4 o[K_ITERS];
    int2 lb[K_ITERS];
#pragma unroll
    for (int k = 0; k < K_ITERS; ++k) {
        const int p = k * BDIM + tid;
        o[k] = rowp4[p];       // (ch0[j0], ch1[j0], ch0[j1], ch1[j1]), j0=2p
        lb[k] = labp2[p];
    }

    float v0[K_ITERS], v1[K_ITERS];
    int zmax = -1;  // last j with temp==0, i.e. !(out1 > out0)  (argmax tie -> 0)
#pragma unroll
    for (int k = 0; k < K_ITERS; ++k) {
        const int p = k * BDIM + tid;
        const int j0 = 2 * p, j1 = j0 + 1;
        // -3.6/log2(j+2) via v_log_f32 + v_rcp_f32 (rel err ~1e-6, OK vs 2.8e-3 thr)
        const float pr0 = -3.6f * __builtin_amdgcn_rcpf(__log2f((float)j0 + 2.0f));
        const float pr1 = -3.6f * __builtin_amdgcn_rcpf(__log2f((float)j1 + 2.0f));
        v0[k] = o[k].y * ((lb[k].x == 1) ? pr0 : 0.065f);
        v1[k] = o[k].w * ((lb[k].y == 1) ? pr1 : 0.065f);
        if (!(o[k].y > o[k].x)) zmax = j0;
        if (!(o[k].w > o[k].z)) zmax = j1;  // j increases with k; later wins = max
    }

    // ---- block-reduce max(zmax) over 8 waves ----
    __shared__ int smax[BDIM / 64];
    __shared__ float ssum[BDIM / 64];
    const int wid = tid >> 6, lane = tid & 63;
#pragma unroll
    for (int off = 32; off; off >>= 1) zmax = max(zmax, __shfl_down(zmax, off));
    if (lane == 0) smax[wid] = zmax;
    __syncthreads();
    int mall = smax[0];
#pragma unroll
    for (int w = 1; w < BDIM / 64; ++w) mall = max(mall, smax[w]);
    const int cut = (mall < 0) ? LROW : mall;  // all-ones row => cut = L

    // ---- conditional sum from registers, block-reduce, store partial ----
    float s = 0.0f;
#pragma unroll
    for (int k = 0; k < K_ITERS; ++k) {
        const int p = k * BDIM + tid;
        const int j0 = 2 * p, j1 = j0 + 1;
        if (j0 < cut) s += v0[k];
        if (j1 < cut) s += v1[k];
    }
#pragma unroll
    for (int off = 32; off; off >>= 1) s += __shfl_down(s, off);
    if (lane == 0) ssum[wid] = s;
    __syncthreads();
    if (tid == 0) {
        float bs = 0.0f;
#pragma unroll
        for (int w = 0; w < BDIM / 64; ++w) bs += ssum[w];
        partial[row] = bs;
    }
}

__global__ __launch_bounds__(256) void bicut_final_kernel(
    const float* __restrict__ partial,
    float* __restrict__ loss) {
    const int tid = threadIdx.x;
    const float4* p4 = reinterpret_cast<const float4*>(partial);
    float s = 0.0f;
#pragma unroll
    for (int k = 0; k < BROW / 4 / 256; ++k) {  // 4096 floats = 1024 float4s
        const float4 v = p4[k * 256 + tid];
        s += v.x + v.y + v.z + v.w;
    }
    __shared__ float ss[4];
    const int wid = tid >> 6, lane = tid & 63;
#pragma unroll
    for (int off = 32; off; off >>= 1) s += __shfl_down(s, off);
    if (lane == 0) ss[wid] = s;
    __syncthreads();
    if (tid == 0) loss[0] = (ss[0] + ss[1] + ss[2] + ss[3]) * (1.0f / (float)BROW);
}

extern "C" void kernel_launch(void* const* d_in, const int* in_sizes, int n_in,
                              void* d_out, int out_size, void* d_ws, size_t ws_size,
                              hipStream_t stream) {
    const float* out = (const float*)d_in[0];
    const int* labels = (const int*)d_in[1];
    float* loss = (float*)d_out;
    float* partial = (float*)d_ws;  // 4096 floats = 16 KB, written before read

    bicut_partial_kernel<<<BROW, BDIM, 0, stream>>>(out, labels, partial);
    bicut_final_kernel<<<1, 256, 0, stream>>>(partial, loss);
}